// Round 5
// baseline (540.800 us; speedup 1.0000x reference)
//
#include <hip/hip_runtime.h>
#include <stddef.h>

// Problem constants (match reference setup_inputs)
constexpr int N_NODES = 200000;
constexpr int N_EDGES = 200000;
constexpr int N_GRAPHS = 128;
constexpr int IN_F = 256;
constexpr int HID_F = 128;
constexpr int OUT_F = 128;
constexpr int OUT_W = OUT_F + HID_F; // 256 output cols per graph
constexpr int SCAN_NB = (N_NODES + 1023) / 1024; // 196 blocks
constexpr int EDGE_NB = (N_EDGES + 255) / 256;   // 782 blocks
constexpr int CHUNKS = 128;                      // mean k-split

typedef __attribute__((ext_vector_type(8))) short short8;   // bf16x8 MFMA A/B frag
typedef __attribute__((ext_vector_type(4))) float float4v;  // fp32x4 MFMA C/D frag

__device__ __forceinline__ short f2bf(float f) {
    union { float f; unsigned u; } v; v.f = f;
    unsigned r = v.u + 0x7fffu + ((v.u >> 16) & 1u);  // RNE
    return (short)(r >> 16);
}
__device__ __forceinline__ float bf2f(unsigned short s) {
    union { unsigned u; float f; } v; v.u = ((unsigned)s) << 16;
    return v.f;
}

// ---------------- consolidated init ----------------
// One launch: memset(cursor), rootlin-zero, bounds, weight transposes.
__global__ __launch_bounds__(256) void init_kernel(
    const int* __restrict__ batch, const float* __restrict__ W1,
    const float* __restrict__ W2,
    int* __restrict__ cursor, float* __restrict__ rootlin,
    int* __restrict__ startv, int* __restrict__ cntg,
    short* __restrict__ Bt1, short* __restrict__ Bt2)
{
    __shared__ int s_start[N_GRAPHS + 1];
    const int t = threadIdx.x;
    const int gid = blockIdx.x * 256 + t;

    if (gid < N_NODES) cursor[gid] = 0;
    if (gid < N_GRAPHS * OUT_F) rootlin[gid] = 0.f;
    if (gid < 128 * IN_F) { // Bt1[n*256+k] = bf16(W1[k*128+n])
        int n = gid >> 8, k = gid & 255;
        Bt1[(size_t)n * IN_F + k] = f2bf(W1[(size_t)k * 128 + n]);
    } else if (gid < 128 * IN_F + 128 * HID_F) {
        int tw = gid - 128 * IN_F;
        int n = tw >> 7, k = tw & 127;
        Bt2[(size_t)n * HID_F + k] = f2bf(W2[(size_t)k * 128 + n]);
    }
    if (blockIdx.x == 0) {
        if (t <= N_GRAPHS) { // lower_bound(batch, g); g==128 -> N_NODES
            int g = t, lo = 0, hi = N_NODES;
            while (lo < hi) {
                int mid = (lo + hi) >> 1;
                if (batch[mid] < g) lo = mid + 1; else hi = mid;
            }
            s_start[t] = lo;
        }
        __syncthreads();
        if (t < N_GRAPHS) {
            startv[t] = s_start[t];
            cntg[t] = s_start[t + 1] - s_start[t];
        }
    }
}

__global__ void edge_prep_kernel(const int* __restrict__ dst, int* __restrict__ cntin, int E) {
    int e = blockIdx.x * blockDim.x + threadIdx.x;
    if (e < E) atomicAdd(&cntin[dst[e]], 1);
}

__global__ __launch_bounds__(1024) void scan_reduce_kernel(const int* __restrict__ cnt,
                                                           int* __restrict__ partial, int n) {
    __shared__ int sm[1024];
    int t = threadIdx.x;
    int i = blockIdx.x * 1024 + t;
    sm[t] = (i < n) ? cnt[i] : 0;
    __syncthreads();
    for (int ofs = 512; ofs > 0; ofs >>= 1) {
        if (t < ofs) sm[t] += sm[t + ofs];
        __syncthreads();
    }
    if (t == 0) partial[blockIdx.x] = sm[0];
}

__global__ void scan_base_kernel(int* __restrict__ partial, int nb) {
    __shared__ int sm[256];
    int t = threadIdx.x;
    sm[t] = (t < nb) ? partial[t] : 0;
    __syncthreads();
    for (int ofs = 1; ofs < 256; ofs <<= 1) {
        int v = (t >= ofs) ? sm[t - ofs] : 0;
        __syncthreads();
        sm[t] += v;
        __syncthreads();
    }
    if (t < nb) partial[t] = (t == 0) ? 0 : sm[t - 1];
}

// local scan + base -> rp[i], cur[i]; fused dinv[i] = rsqrt(1+indeg).
// cnt aliases cur: each thread reads cnt[i] before writing cur[i] (same index).
__global__ __launch_bounds__(1024) void scan_final_kernel(const int* __restrict__ cnt,
                                                          const int* __restrict__ partial,
                                                          int* __restrict__ rp,
                                                          int* __restrict__ cur,
                                                          float* __restrict__ dinv, int n) {
    __shared__ int sm[1024];
    int t = threadIdx.x;
    int i = blockIdx.x * 1024 + t;
    int v = (i < n) ? cnt[i] : 0;
    sm[t] = v;
    __syncthreads();
    for (int ofs = 1; ofs < 1024; ofs <<= 1) {
        int u = (t >= ofs) ? sm[t - ofs] : 0;
        __syncthreads();
        sm[t] += u;
        __syncthreads();
    }
    int base = partial[blockIdx.x];
    if (i < n) {
        int ex = base + sm[t] - v; // exclusive
        rp[i] = ex;
        cur[i] = ex;
        dinv[i] = rsqrtf(1.0f + (float)v);
        if (i == n - 1) rp[n] = ex + v;
    }
}

// Fused bucket + rootlin: blocks [0,782) bucket edges; blocks [782,1038)
// compute rootlin partial sums (64-k slices) via atomicAdd into zeroed rootlin.
__global__ __launch_bounds__(256) void bucket_rootlin_kernel(
    const int* __restrict__ src, const int* __restrict__ dst,
    int* __restrict__ cur, int* __restrict__ adj,
    const float* __restrict__ x, const int* __restrict__ root_index,
    const float* __restrict__ W2, float* __restrict__ rootlin)
{
    int b = blockIdx.x;
    int t = threadIdx.x;
    if (b < EDGE_NB) {
        int e = b * 256 + t;
        if (e < N_EDGES) {
            int pos = atomicAdd(&cur[dst[e]], 1);
            adj[pos] = src[e];
        }
    } else {
        int rb = b - EDGE_NB;          // 0..255
        int g = rb >> 1;
        int f = t & 127;
        int k0 = (rb & 1) * 128 + (t >> 7) * 64;
        int r = root_index[g];
        const float* xr = x + (size_t)r * IN_F;
        float acc = 0.f;
        for (int k = k0; k < k0 + 64; ++k)
            acc += fmaxf(xr[k], 0.f) * W2[(size_t)(HID_F + k) * OUT_F + f];
        atomicAdd(&rootlin[(size_t)g * OUT_F + f], acc);
    }
}

// ---------------- bf16 MFMA GEMM (r5: no B in LDS) ----------------
// out[M,128] = op(A)[M,KTOT] @ B[KTOT,128], epilogue v = dinv[row]*(acc [+ rootlin]),
// stored bf16.
// r5 restructure: Bt is tiny (32-64KB) and L2-resident; its transposed layout
// makes every MFMA B-fragment a contiguous 16B load -> load B frags straight
// from L2, drop Bs LDS (52.2->17.4 KB). Occupancy 3 -> 4-6 blocks/CU; one less
// staged buffer behind each barrier. Trailing barrier skipped on last K-chunk.
// GATHER (conv2): A-element for row d, col k is
//   relu(dinv[d]*(hs1[d,k] + sum_{in-edges} hs1[adj,k]) + bvec[k])  — pull-mode.
template<int KTOT, bool GATHER, bool ADDROOT>
__global__ __launch_bounds__(256, 4) void mfma_gemm_kernel(
    const void* __restrict__ Ap, const short* __restrict__ Bt,
    unsigned short* __restrict__ outp,
    const float* __restrict__ dinv, const float* __restrict__ bvec,
    const float* __restrict__ rootlin, const int* __restrict__ batch,
    const int* __restrict__ rp, const int* __restrict__ adj)
{
    // stride 136 shorts = 272B: bank stride 68 == 4 mod 32 -> 2-way conflicts only (free, m136)
    __shared__ __align__(16) short As[64][136];

    const int tid = threadIdx.x;
    const int wave = tid >> 6;
    const int lane = tid & 63;
    const int quad = lane >> 4;
    const int l16  = lane & 15;
    const int row0 = blockIdx.x * 64;

    float4v acc[8];
    #pragma unroll
    for (int c = 0; c < 8; ++c) acc[c] = (float4v){0.f, 0.f, 0.f, 0.f};

    // A staging: 4 threads per row; thread covers cols {ac8+32*jj .. +7}, jj=0..3
    const int arow = tid >> 2;
    const int ac8 = (tid & 3) * 8;
    constexpr int NKB = KTOT / 128;

    for (int kb = 0; kb < NKB; ++kb) {
        if (GATHER) {
            // conv2 aggregation pulled via CSR from bf16 hs1; KTOT==128 so kb==0
            const unsigned short* A = (const unsigned short*)Ap;
            const int row = row0 + arow;
            float sum[4][8];
            const unsigned short* hp = A + (size_t)row * 128 + ac8;
            #pragma unroll
            for (int jj = 0; jj < 4; ++jj) {
                short8 h = *(const short8*)(hp + 32 * jj);
                #pragma unroll
                for (int q = 0; q < 8; ++q) sum[jj][q] = bf2f((unsigned short)h[q]);
            }
            int e0 = rp[row], e1 = rp[row + 1];
            for (int e = e0; e < e1; ++e) {
                const unsigned short* qp = A + (size_t)adj[e] * 128 + ac8;
                #pragma unroll
                for (int jj = 0; jj < 4; ++jj) {
                    short8 h = *(const short8*)(qp + 32 * jj);
                    #pragma unroll
                    for (int q = 0; q < 8; ++q) sum[jj][q] += bf2f((unsigned short)h[q]);
                }
            }
            float asc = dinv[row];
            #pragma unroll
            for (int jj = 0; jj < 4; ++jj) {
                const float* bv = bvec + ac8 + 32 * jj;
                short8 s;
                #pragma unroll
                for (int q = 0; q < 8; ++q)
                    s[q] = f2bf(fmaxf(asc * sum[jj][q] + bv[q], 0.f));
                *(short8*)&As[arow][ac8 + 32 * jj] = s;
            }
        } else {
            const float* A = (const float*)Ap;
            const float* ap = A + (size_t)(row0 + arow) * KTOT + kb * 128 + ac8;
            #pragma unroll
            for (int jj = 0; jj < 4; ++jj) {
                float4 f0 = *(const float4*)(ap + 32 * jj);
                float4 f1 = *(const float4*)(ap + 32 * jj + 4);
                short8 s;
                s[0] = f2bf(f0.x); s[1] = f2bf(f0.y); s[2] = f2bf(f0.z); s[3] = f2bf(f0.w);
                s[4] = f2bf(f1.x); s[5] = f2bf(f1.y); s[6] = f2bf(f1.z); s[7] = f2bf(f1.w);
                *(short8*)&As[arow][ac8 + 32 * jj] = s;
            }
        }
        __syncthreads();
        #pragma unroll
        for (int ks = 0; ks < 4; ++ks) {
            // A frag: A[m=l16][k=ks*32+quad*8+j]  (m89-verified layout)
            short8 af = *(const short8*)&As[wave * 16 + l16][ks * 32 + quad * 8];
            // B frag straight from L2-resident Bt: B[k][n=c*16+l16] = Bt[n*KTOT + k],
            // contiguous 16B along k. Same values the old LDS path staged.
            const short* bbase = Bt + kb * 128 + ks * 32 + quad * 8;
            #pragma unroll
            for (int c = 0; c < 8; ++c) {
                short8 bf = *(const short8*)(bbase + (c * 16 + l16) * KTOT);
                acc[c] = __builtin_amdgcn_mfma_f32_16x16x32_bf16(af, bf, acc[c], 0, 0, 0);
            }
        }
        if (kb + 1 < NKB) __syncthreads(); // protect As rewrite only
    }

    // epilogue: D[row=quad*4+r][col=c*16+l16] (m89-verified C/D layout); bf16 store
    #pragma unroll
    for (int r = 0; r < 4; ++r) {
        int row = row0 + wave * 16 + quad * 4 + r;
        float di = dinv[row];
        const float* rl = nullptr;
        if (ADDROOT) rl = rootlin + (size_t)batch[row] * 128;
        #pragma unroll
        for (int c = 0; c < 8; ++c) {
            int col = c * 16 + l16;
            float v = acc[c][r];
            if (ADDROOT) v += rl[col];
            outp[(size_t)row * 128 + col] = (unsigned short)f2bf(v * di);
        }
    }
}

// pmean[c][g][f] = chunk-sum over nodes of relu(dinv[i]*(hs2[i]+sum_in hs2[adj]) + b2)
// out[g,128:256] = n>0 ? dinv[r]*(hs1[r]+sum_in hs1[adj]) + b1 : 0   (c==0 blocks)
__global__ void mean_kernel(const unsigned short* __restrict__ hs2,
                            const unsigned short* __restrict__ hs1,
                            const float* __restrict__ dinv, const float* __restrict__ b1v,
                            const float* __restrict__ b2v, const int* __restrict__ root_index,
                            const int* __restrict__ cnt, const int* __restrict__ start,
                            const int* __restrict__ rp, const int* __restrict__ adj,
                            float* __restrict__ pmean, float* __restrict__ out)
{
    int g = blockIdx.x;
    int c = blockIdx.y;
    int f = threadIdx.x; // 128
    int s = start[g], n = cnt[g];
    int per = (n + CHUNKS - 1) / CHUNKS;
    int lo = s + c * per;
    int hi = min(s + n, lo + per);
    float bb = b2v[f];
    float accv = 0.f;
    for (int i = lo; i < hi; ++i) {
        float v = bf2f(hs2[(size_t)i * 128 + f]);
        int e0 = rp[i], e1 = rp[i + 1];
        for (int e = e0; e < e1; ++e)
            v += bf2f(hs2[(size_t)adj[e] * 128 + f]);
        accv += fmaxf(dinv[i] * v + bb, 0.f);
    }
    pmean[(size_t)c * (N_GRAPHS * 128) + g * 128 + f] = accv; // always stored
    if (c == 0) {
        int r = root_index[g];
        float v = 0.f;
        if (n > 0) {
            v = bf2f(hs1[(size_t)r * 128 + f]);
            int e0 = rp[r], e1 = rp[r + 1];
            for (int e = e0; e < e1; ++e)
                v += bf2f(hs1[(size_t)adj[e] * 128 + f]);
            v = dinv[r] * v + b1v[f];
        }
        out[(size_t)g * OUT_W + HID_F + f] = v;
    }
}

// out[g,0:128] = (1/n) * sum_c pmean[c][g][f]
__global__ void meanreduce_kernel(const float* __restrict__ pmean,
                                  const int* __restrict__ cnt,
                                  float* __restrict__ out)
{
    int g = blockIdx.x;
    int f = threadIdx.x;
    float s = 0.f;
    for (int c = 0; c < CHUNKS; ++c)
        s += pmean[(size_t)c * (N_GRAPHS * 128) + g * 128 + f];
    out[(size_t)g * OUT_W + f] = s / (float)max(cnt[g], 1);
}

// ---------------- launch ----------------

static inline size_t align_up(size_t x, size_t a) { return (x + a - 1) / a * a; }

extern "C" void kernel_launch(void* const* d_in, const int* in_sizes, int n_in,
                              void* d_out, int out_size, void* d_ws, size_t ws_size,
                              hipStream_t stream) {
    const float* x = (const float*)d_in[0];
    const int* ei = (const int*)d_in[1];
    const int* batch = (const int*)d_in[2];
    const int* root = (const int*)d_in[3];
    const float* W1 = (const float*)d_in[4];
    const float* b1 = (const float*)d_in[5];
    const float* W2 = (const float*)d_in[6];
    const float* b2 = (const float*)d_in[7];
    float* out = (float*)d_out;

    const int* src = ei;
    const int* dst = ei + N_EDGES;

    // workspace carve-up
    char* ws = (char*)d_ws;
    size_t off = 0;
    const size_t NB16 = (size_t)N_NODES * 128 * sizeof(unsigned short); // 51.2 MB

    float* dinv = (float*)(ws + off);    off = align_up(off + (size_t)N_NODES * sizeof(float), 256);
    int* cntg = (int*)(ws + off);        off = align_up(off + N_GRAPHS * sizeof(int), 256);
    int* startv = (int*)(ws + off);      off = align_up(off + N_GRAPHS * sizeof(int), 256);
    float* rootlin = (float*)(ws + off); off = align_up(off + (size_t)N_GRAPHS * OUT_F * sizeof(float), 256);
    short* Bt1 = (short*)(ws + off);     off = align_up(off + (size_t)128 * IN_F * sizeof(short), 256);
    short* Bt2 = (short*)(ws + off);     off = align_up(off + (size_t)128 * HID_F * sizeof(short), 256);
    int* rowptr = (int*)(ws + off);      off = align_up(off + (size_t)(N_NODES + 1) * sizeof(int), 256);
    int* cursor = (int*)(ws + off);      off = align_up(off + (size_t)N_NODES * sizeof(int), 256);
    int* partial = (int*)(ws + off);     off = align_up(off + (size_t)SCAN_NB * sizeof(int), 256);
    int* adj = (int*)(ws + off);         off = align_up(off + (size_t)N_EDGES * sizeof(int), 256);
    float* pmean = (float*)(ws + off);   off = align_up(off + (size_t)CHUNKS * N_GRAPHS * 128 * sizeof(float), 256);
    unsigned short* hs1 = (unsigned short*)(ws + off);  off = align_up(off + NB16, 256);
    unsigned short* hs2 = (unsigned short*)(ws + off);  off = align_up(off + NB16, 256);
    (void)ws_size; (void)n_in; (void)in_sizes; (void)out_size;

    // consolidated init: cursor-zero, rootlin-zero, bounds, weight transposes
    init_kernel<<<EDGE_NB, 256, 0, stream>>>(batch, W1, W2, cursor, rootlin,
                                             startv, cntg, Bt1, Bt2);
    // in-degree -> CSR-by-dst via hierarchical scan (+ fused dinv)
    edge_prep_kernel<<<EDGE_NB, 256, 0, stream>>>(dst, cursor, N_EDGES);
    scan_reduce_kernel<<<SCAN_NB, 1024, 0, stream>>>(cursor, partial, N_NODES);
    scan_base_kernel<<<1, 256, 0, stream>>>(partial, SCAN_NB);
    scan_final_kernel<<<SCAN_NB, 1024, 0, stream>>>(cursor, partial, rowptr, cursor, dinv, N_NODES);
    // bucket edges + rootlin in one launch
    bucket_rootlin_kernel<<<EDGE_NB + 2 * N_GRAPHS, 256, 0, stream>>>(
        src, dst, cursor, adj, x, root, W2, rootlin);

    // conv1 linear: hs1 = bf16( dinv .* (x @ W1) )
    mfma_gemm_kernel<IN_F, false, false><<<N_NODES / 64, 256, 0, stream>>>(
        x, Bt1, hs1, dinv, nullptr, nullptr, nullptr, nullptr, nullptr);

    // conv2 linear with CSR gather fused into A-staging (r5: back to fused now
    // that occupancy is 4-6 blocks/CU; saves hsag read+write, one launch):
    // hs2 = bf16( dinv .* ( relu(dinv.*(hs1+gather)+b1) @ W2[0:128] + rootlin[batch] ) )
    mfma_gemm_kernel<HID_F, true, true><<<N_NODES / 64, 256, 0, stream>>>(
        hs1, Bt2, hs2, dinv, b1, rootlin, batch, rowptr, adj);

    // conv2-aggregation + relu + graph mean partials + root gather (atomic-free)
    dim3 mg(N_GRAPHS, CHUNKS);
    mean_kernel<<<mg, 128, 0, stream>>>(hs2, hs1, dinv, b1, b2, root, cntg, startv,
                                        rowptr, adj, pmean, out);
    meanreduce_kernel<<<N_GRAPHS, 128, 0, stream>>>(pmean, cntg, out);
}

// Round 6
// 479.686 us; speedup vs baseline: 1.1274x; 1.1274x over previous
//
#include <hip/hip_runtime.h>
#include <stddef.h>

// Problem constants (match reference setup_inputs)
constexpr int N_NODES = 200000;
constexpr int N_EDGES = 200000;
constexpr int N_GRAPHS = 128;
constexpr int IN_F = 256;
constexpr int HID_F = 128;
constexpr int OUT_F = 128;
constexpr int OUT_W = OUT_F + HID_F; // 256 output cols per graph
constexpr int SCAN_NB = (N_NODES + 1023) / 1024; // 196 blocks
constexpr int EDGE_NB = (N_EDGES + 255) / 256;   // 782 blocks
constexpr int CHUNKS = 128;                      // mean k-split

typedef __attribute__((ext_vector_type(8))) short short8;   // bf16x8 MFMA A/B frag
typedef __attribute__((ext_vector_type(4))) float float4v;  // fp32x4 MFMA C/D frag

__device__ __forceinline__ short f2bf(float f) {
    union { float f; unsigned u; } v; v.f = f;
    unsigned r = v.u + 0x7fffu + ((v.u >> 16) & 1u);  // RNE
    return (short)(r >> 16);
}
__device__ __forceinline__ float bf2f(unsigned short s) {
    union { unsigned u; float f; } v; v.u = ((unsigned)s) << 16;
    return v.f;
}

// ---------------- consolidated init ----------------
// One launch: memset(cursor), rootlin-zero, bounds, weight transposes.
__global__ __launch_bounds__(256) void init_kernel(
    const int* __restrict__ batch, const float* __restrict__ W1,
    const float* __restrict__ W2,
    int* __restrict__ cursor, float* __restrict__ rootlin,
    int* __restrict__ startv, int* __restrict__ cntg,
    short* __restrict__ Bt1, short* __restrict__ Bt2)
{
    __shared__ int s_start[N_GRAPHS + 1];
    const int t = threadIdx.x;
    const int gid = blockIdx.x * 256 + t;

    if (gid < N_NODES) cursor[gid] = 0;
    if (gid < N_GRAPHS * OUT_F) rootlin[gid] = 0.f;
    if (gid < 128 * IN_F) { // Bt1[n*256+k] = bf16(W1[k*128+n])
        int n = gid >> 8, k = gid & 255;
        Bt1[(size_t)n * IN_F + k] = f2bf(W1[(size_t)k * 128 + n]);
    } else if (gid < 128 * IN_F + 128 * HID_F) {
        int tw = gid - 128 * IN_F;
        int n = tw >> 7, k = tw & 127;
        Bt2[(size_t)n * HID_F + k] = f2bf(W2[(size_t)k * 128 + n]);
    }
    if (blockIdx.x == 0) {
        if (t <= N_GRAPHS) { // lower_bound(batch, g); g==128 -> N_NODES
            int g = t, lo = 0, hi = N_NODES;
            while (lo < hi) {
                int mid = (lo + hi) >> 1;
                if (batch[mid] < g) lo = mid + 1; else hi = mid;
            }
            s_start[t] = lo;
        }
        __syncthreads();
        if (t < N_GRAPHS) {
            startv[t] = s_start[t];
            cntg[t] = s_start[t + 1] - s_start[t];
        }
    }
}

__global__ void edge_prep_kernel(const int* __restrict__ dst, int* __restrict__ cntin, int E) {
    int e = blockIdx.x * blockDim.x + threadIdx.x;
    if (e < E) atomicAdd(&cntin[dst[e]], 1);
}

__global__ __launch_bounds__(1024) void scan_reduce_kernel(const int* __restrict__ cnt,
                                                           int* __restrict__ partial, int n) {
    __shared__ int sm[1024];
    int t = threadIdx.x;
    int i = blockIdx.x * 1024 + t;
    sm[t] = (i < n) ? cnt[i] : 0;
    __syncthreads();
    for (int ofs = 512; ofs > 0; ofs >>= 1) {
        if (t < ofs) sm[t] += sm[t + ofs];
        __syncthreads();
    }
    if (t == 0) partial[blockIdx.x] = sm[0];
}

__global__ void scan_base_kernel(int* __restrict__ partial, int nb) {
    __shared__ int sm[256];
    int t = threadIdx.x;
    sm[t] = (t < nb) ? partial[t] : 0;
    __syncthreads();
    for (int ofs = 1; ofs < 256; ofs <<= 1) {
        int v = (t >= ofs) ? sm[t - ofs] : 0;
        __syncthreads();
        sm[t] += v;
        __syncthreads();
    }
    if (t < nb) partial[t] = (t == 0) ? 0 : sm[t - 1];
}

// local scan + base -> rp[i], cur[i]; fused dinv[i] = rsqrt(1+indeg).
// cnt aliases cur: each thread reads cnt[i] before writing cur[i] (same index).
__global__ __launch_bounds__(1024) void scan_final_kernel(const int* __restrict__ cnt,
                                                          const int* __restrict__ partial,
                                                          int* __restrict__ rp,
                                                          int* __restrict__ cur,
                                                          float* __restrict__ dinv, int n) {
    __shared__ int sm[1024];
    int t = threadIdx.x;
    int i = blockIdx.x * 1024 + t;
    int v = (i < n) ? cnt[i] : 0;
    sm[t] = v;
    __syncthreads();
    for (int ofs = 1; ofs < 1024; ofs <<= 1) {
        int u = (t >= ofs) ? sm[t - ofs] : 0;
        __syncthreads();
        sm[t] += u;
        __syncthreads();
    }
    int base = partial[blockIdx.x];
    if (i < n) {
        int ex = base + sm[t] - v; // exclusive
        rp[i] = ex;
        cur[i] = ex;
        dinv[i] = rsqrtf(1.0f + (float)v);
        if (i == n - 1) rp[n] = ex + v;
    }
}

// Fused bucket + rootlin: blocks [0,782) bucket edges; blocks [782,1038)
// compute rootlin partial sums (64-k slices) via atomicAdd into zeroed rootlin.
__global__ __launch_bounds__(256) void bucket_rootlin_kernel(
    const int* __restrict__ src, const int* __restrict__ dst,
    int* __restrict__ cur, int* __restrict__ adj,
    const float* __restrict__ x, const int* __restrict__ root_index,
    const float* __restrict__ W2, float* __restrict__ rootlin)
{
    int b = blockIdx.x;
    int t = threadIdx.x;
    if (b < EDGE_NB) {
        int e = b * 256 + t;
        if (e < N_EDGES) {
            int pos = atomicAdd(&cur[dst[e]], 1);
            adj[pos] = src[e];
        }
    } else {
        int rb = b - EDGE_NB;          // 0..255
        int g = rb >> 1;
        int f = t & 127;
        int k0 = (rb & 1) * 128 + (t >> 7) * 64;
        int r = root_index[g];
        const float* xr = x + (size_t)r * IN_F;
        float acc = 0.f;
        for (int k = k0; k < k0 + 64; ++k)
            acc += fmaxf(xr[k], 0.f) * W2[(size_t)(HID_F + k) * OUT_F + f];
        atomicAdd(&rootlin[(size_t)g * OUT_F + f], acc);
    }
}

// ---------------- conv2 aggregation, standalone (r6: re-split from GEMM) ----------------
// hsag[d,k] = bf16( relu( dinv[d]*(hs1[d,k] + sum_in hs1[adj,k]) + b1[k] ) )
// No LDS, no barriers: 8 threads/row, 1.6M threads -> TLP hides gather latency.
// (r5 post-mortem: fusing this into the barrier-synced GEMM A-staging = 147us,
// latency-bound at 1 TB/s; the max-degree row stalls the whole tile.)
__global__ __launch_bounds__(256) void agg2_kernel(
    const unsigned short* __restrict__ hs1, const float* __restrict__ dinv,
    const float* __restrict__ b1v, const int* __restrict__ rp,
    const int* __restrict__ adj, unsigned short* __restrict__ hsag)
{
    int gid = blockIdx.x * 256 + threadIdx.x; // N_NODES*8 threads exactly
    int r = gid >> 3;
    int c0 = (gid & 7) * 16; // 16 shorts = 32B per thread
    const unsigned short* hp = hs1 + (size_t)r * 128 + c0;
    float sum[16];
    {
        short8 h0 = *(const short8*)hp;
        short8 h1 = *(const short8*)(hp + 8);
        #pragma unroll
        for (int q = 0; q < 8; ++q) {
            sum[q] = bf2f((unsigned short)h0[q]);
            sum[8 + q] = bf2f((unsigned short)h1[q]);
        }
    }
    int e0 = rp[r], e1 = rp[r + 1];
    for (int e = e0; e < e1; ++e) {
        const unsigned short* qp = hs1 + (size_t)adj[e] * 128 + c0;
        short8 h0 = *(const short8*)qp;
        short8 h1 = *(const short8*)(qp + 8);
        #pragma unroll
        for (int q = 0; q < 8; ++q) {
            sum[q] += bf2f((unsigned short)h0[q]);
            sum[8 + q] += bf2f((unsigned short)h1[q]);
        }
    }
    float di = dinv[r];
    short8 s0, s1;
    #pragma unroll
    for (int q = 0; q < 8; ++q) {
        s0[q] = f2bf(fmaxf(di * sum[q] + b1v[c0 + q], 0.f));
        s1[q] = f2bf(fmaxf(di * sum[8 + q] + b1v[c0 + 8 + q], 0.f));
    }
    unsigned short* op = hsag + (size_t)r * 128 + c0;
    *(short8*)op = s0;
    *(short8*)(op + 8) = s1;
}

// ---------------- bf16 MFMA GEMM (r6: A direct-from-global, B in LDS) ----------------
// out[M,128] = op(A)[M,KTOT] @ B[KTOT,128], epilogue v = dinv[row]*(acc [+ rootlin]),
// stored bf16.
// r6 restructure (from r5 counters: MfmaUtil 3.4%, 1.2M LDS conflicts, latency-bound):
//  - B stays in LDS (r5 lesson: streaming kernels thrash L2 -> per-MFMA B loads
//    from "L2-resident" Bt actually hit HBM). Staged per 128-k chunk.
//  - A has ZERO cross-thread reuse -> no As LDS at all. Each lane loads its own
//    m89-layout fragment A[row0+wave*16+l16][kb*128+ks*32+quad*8 .. +7] straight
//    from global (fp32: 32B + in-register f2bf; bf16: one 16B load) and reuses it
//    for the 8 n-column MFMAs. Deletes all A-staging barriers + bank conflicts.
//  - Barriers: conv2 (KTOT=128) has exactly 1; conv1 (KTOT=256) has 3.
//  - LDS 34.8KB -> 4 blocks/CU.
template<int KTOT, bool ABF16, bool ADDROOT>
__global__ __launch_bounds__(256, 4) void mfma_gemm_kernel(
    const void* __restrict__ Ap, const short* __restrict__ Bt,
    unsigned short* __restrict__ outp,
    const float* __restrict__ dinv,
    const float* __restrict__ rootlin, const int* __restrict__ batch)
{
    // stride 136 shorts = 272B: bank stride 68 == 4 mod 32 -> 2-way conflicts only (free, m136)
    __shared__ __align__(16) short Bs[128][136];

    const int tid = threadIdx.x;
    const int wave = tid >> 6;
    const int lane = tid & 63;
    const int quad = lane >> 4;
    const int l16  = lane & 15;
    const int row0 = blockIdx.x * 64;
    const int arow = row0 + wave * 16 + l16;  // this lane's A row (m89 layout)

    float4v acc[8];
    #pragma unroll
    for (int c = 0; c < 8; ++c) acc[c] = (float4v){0.f, 0.f, 0.f, 0.f};

    // B staging split: thread -> (n, 64-k half)
    const int bn = tid >> 1;
    const int bk = (tid & 1) * 64;
    constexpr int NKB = KTOT / 128;

    for (int kb = 0; kb < NKB; ++kb) {
        {
            const short* bp = Bt + (size_t)bn * KTOT + kb * 128 + bk;
            #pragma unroll
            for (int j = 0; j < 8; ++j)
                *(short8*)&Bs[bn][bk + 8 * j] = *(const short8*)(bp + 8 * j);
        }
        __syncthreads();
        #pragma unroll
        for (int ks = 0; ks < 4; ++ks) {
            // A frag direct from global: A[arow][kb*128 + ks*32 + quad*8 + j]
            short8 af;
            if (ABF16) {
                const unsigned short* ap = (const unsigned short*)Ap
                    + (size_t)arow * KTOT + kb * 128 + ks * 32 + quad * 8;
                af = *(const short8*)ap;
            } else {
                const float* ap = (const float*)Ap
                    + (size_t)arow * KTOT + kb * 128 + ks * 32 + quad * 8;
                float4 f0 = *(const float4*)ap;
                float4 f1 = *(const float4*)(ap + 4);
                af[0] = f2bf(f0.x); af[1] = f2bf(f0.y); af[2] = f2bf(f0.z); af[3] = f2bf(f0.w);
                af[4] = f2bf(f1.x); af[5] = f2bf(f1.y); af[6] = f2bf(f1.z); af[7] = f2bf(f1.w);
            }
            #pragma unroll
            for (int c = 0; c < 8; ++c) {
                // B frag: B[k=ks*32+quad*8+j][n=c*16+l16]
                short8 bf = *(const short8*)&Bs[c * 16 + l16][ks * 32 + quad * 8];
                acc[c] = __builtin_amdgcn_mfma_f32_16x16x32_bf16(af, bf, acc[c], 0, 0, 0);
            }
        }
        if (kb + 1 < NKB) __syncthreads(); // protect Bs rewrite only
    }

    // epilogue: D[row=quad*4+r][col=c*16+l16] (m89-verified C/D layout); bf16 store
    #pragma unroll
    for (int r = 0; r < 4; ++r) {
        int row = row0 + wave * 16 + quad * 4 + r;
        float di = dinv[row];
        const float* rl = nullptr;
        if (ADDROOT) rl = rootlin + (size_t)batch[row] * 128;
        #pragma unroll
        for (int c = 0; c < 8; ++c) {
            int col = c * 16 + l16;
            float v = acc[c][r];
            if (ADDROOT) v += rl[col];
            outp[(size_t)row * 128 + col] = (unsigned short)f2bf(v * di);
        }
    }
}

// pmean[c][g][f] = chunk-sum over nodes of relu(dinv[i]*(hs2[i]+sum_in hs2[adj]) + b2)
// out[g,128:256] = n>0 ? dinv[r]*(hs1[r]+sum_in hs1[adj]) + b1 : 0   (c==0 blocks)
__global__ void mean_kernel(const unsigned short* __restrict__ hs2,
                            const unsigned short* __restrict__ hs1,
                            const float* __restrict__ dinv, const float* __restrict__ b1v,
                            const float* __restrict__ b2v, const int* __restrict__ root_index,
                            const int* __restrict__ cnt, const int* __restrict__ start,
                            const int* __restrict__ rp, const int* __restrict__ adj,
                            float* __restrict__ pmean, float* __restrict__ out)
{
    int g = blockIdx.x;
    int c = blockIdx.y;
    int f = threadIdx.x; // 128
    int s = start[g], n = cnt[g];
    int per = (n + CHUNKS - 1) / CHUNKS;
    int lo = s + c * per;
    int hi = min(s + n, lo + per);
    float bb = b2v[f];
    float accv = 0.f;
    for (int i = lo; i < hi; ++i) {
        float v = bf2f(hs2[(size_t)i * 128 + f]);
        int e0 = rp[i], e1 = rp[i + 1];
        for (int e = e0; e < e1; ++e)
            v += bf2f(hs2[(size_t)adj[e] * 128 + f]);
        accv += fmaxf(dinv[i] * v + bb, 0.f);
    }
    pmean[(size_t)c * (N_GRAPHS * 128) + g * 128 + f] = accv; // always stored
    if (c == 0) {
        int r = root_index[g];
        float v = 0.f;
        if (n > 0) {
            v = bf2f(hs1[(size_t)r * 128 + f]);
            int e0 = rp[r], e1 = rp[r + 1];
            for (int e = e0; e < e1; ++e)
                v += bf2f(hs1[(size_t)adj[e] * 128 + f]);
            v = dinv[r] * v + b1v[f];
        }
        out[(size_t)g * OUT_W + HID_F + f] = v;
    }
}

// out[g,0:128] = (1/n) * sum_c pmean[c][g][f]
__global__ void meanreduce_kernel(const float* __restrict__ pmean,
                                  const int* __restrict__ cnt,
                                  float* __restrict__ out)
{
    int g = blockIdx.x;
    int f = threadIdx.x;
    float s = 0.f;
    for (int c = 0; c < CHUNKS; ++c)
        s += pmean[(size_t)c * (N_GRAPHS * 128) + g * 128 + f];
    out[(size_t)g * OUT_W + f] = s / (float)max(cnt[g], 1);
}

// ---------------- launch ----------------

static inline size_t align_up(size_t x, size_t a) { return (x + a - 1) / a * a; }

extern "C" void kernel_launch(void* const* d_in, const int* in_sizes, int n_in,
                              void* d_out, int out_size, void* d_ws, size_t ws_size,
                              hipStream_t stream) {
    const float* x = (const float*)d_in[0];
    const int* ei = (const int*)d_in[1];
    const int* batch = (const int*)d_in[2];
    const int* root = (const int*)d_in[3];
    const float* W1 = (const float*)d_in[4];
    const float* b1 = (const float*)d_in[5];
    const float* W2 = (const float*)d_in[6];
    const float* b2 = (const float*)d_in[7];
    float* out = (float*)d_out;

    const int* src = ei;
    const int* dst = ei + N_EDGES;

    // workspace carve-up
    char* ws = (char*)d_ws;
    size_t off = 0;
    const size_t NB16 = (size_t)N_NODES * 128 * sizeof(unsigned short); // 51.2 MB

    float* dinv = (float*)(ws + off);    off = align_up(off + (size_t)N_NODES * sizeof(float), 256);
    int* cntg = (int*)(ws + off);        off = align_up(off + N_GRAPHS * sizeof(int), 256);
    int* startv = (int*)(ws + off);      off = align_up(off + N_GRAPHS * sizeof(int), 256);
    float* rootlin = (float*)(ws + off); off = align_up(off + (size_t)N_GRAPHS * OUT_F * sizeof(float), 256);
    short* Bt1 = (short*)(ws + off);     off = align_up(off + (size_t)128 * IN_F * sizeof(short), 256);
    short* Bt2 = (short*)(ws + off);     off = align_up(off + (size_t)128 * HID_F * sizeof(short), 256);
    int* rowptr = (int*)(ws + off);      off = align_up(off + (size_t)(N_NODES + 1) * sizeof(int), 256);
    int* cursor = (int*)(ws + off);      off = align_up(off + (size_t)N_NODES * sizeof(int), 256);
    int* partial = (int*)(ws + off);     off = align_up(off + (size_t)SCAN_NB * sizeof(int), 256);
    int* adj = (int*)(ws + off);         off = align_up(off + (size_t)N_EDGES * sizeof(int), 256);
    float* pmean = (float*)(ws + off);   off = align_up(off + (size_t)CHUNKS * N_GRAPHS * 128 * sizeof(float), 256);
    unsigned short* hs1 = (unsigned short*)(ws + off);  off = align_up(off + NB16, 256);
    unsigned short* hs2 = (unsigned short*)(ws + off);  off = align_up(off + NB16, 256);
    unsigned short* hsag = (unsigned short*)(ws + off); off = align_up(off + NB16, 256);
    (void)ws_size; (void)n_in; (void)in_sizes; (void)out_size;

    // consolidated init: cursor-zero, rootlin-zero, bounds, weight transposes
    init_kernel<<<EDGE_NB, 256, 0, stream>>>(batch, W1, W2, cursor, rootlin,
                                             startv, cntg, Bt1, Bt2);
    // in-degree -> CSR-by-dst via hierarchical scan (+ fused dinv)
    edge_prep_kernel<<<EDGE_NB, 256, 0, stream>>>(dst, cursor, N_EDGES);
    scan_reduce_kernel<<<SCAN_NB, 1024, 0, stream>>>(cursor, partial, N_NODES);
    scan_base_kernel<<<1, 256, 0, stream>>>(partial, SCAN_NB);
    scan_final_kernel<<<SCAN_NB, 1024, 0, stream>>>(cursor, partial, rowptr, cursor, dinv, N_NODES);
    // bucket edges + rootlin in one launch
    bucket_rootlin_kernel<<<EDGE_NB + 2 * N_GRAPHS, 256, 0, stream>>>(
        src, dst, cursor, adj, x, root, W2, rootlin);

    // conv1 linear: hs1 = bf16( dinv .* (x @ W1) )
    mfma_gemm_kernel<IN_F, false, false><<<N_NODES / 64, 256, 0, stream>>>(
        x, Bt1, hs1, dinv, nullptr, nullptr);

    // conv2 aggregation (standalone, barrier-free): hsag = relu(dinv.*(hs1+gather)+b1)
    agg2_kernel<<<(N_NODES * 8) / 256, 256, 0, stream>>>(hs1, dinv, b1, rowptr, adj, hsag);

    // conv2 linear (pure streaming bf16 GEMM):
    // hs2 = bf16( dinv .* ( hsag @ W2[0:128] + rootlin[batch] ) )
    mfma_gemm_kernel<HID_F, true, true><<<N_NODES / 64, 256, 0, stream>>>(
        hsag, Bt2, hs2, dinv, rootlin, batch);

    // conv2-aggregation + relu + graph mean partials + root gather (atomic-free)
    dim3 mg(N_GRAPHS, CHUNKS);
    mean_kernel<<<mg, 128, 0, stream>>>(hs2, hs1, dinv, b1, b2, root, cntg, startv,
                                        rowptr, adj, pmean, out);
    meanreduce_kernel<<<N_GRAPHS, 128, 0, stream>>>(pmean, cntg, out);
}

// Round 7
// 441.721 us; speedup vs baseline: 1.2243x; 1.0859x over previous
//
#include <hip/hip_runtime.h>
#include <stddef.h>

// Problem constants (match reference setup_inputs)
constexpr int N_NODES = 200000;
constexpr int N_EDGES = 200000;
constexpr int N_GRAPHS = 128;
constexpr int IN_F = 256;
constexpr int HID_F = 128;
constexpr int OUT_F = 128;
constexpr int OUT_W = OUT_F + HID_F; // 256 output cols per graph
constexpr int SCAN_NB = (N_NODES + 1023) / 1024; // 196 blocks
constexpr int EDGE_NB = (N_EDGES + 255) / 256;   // 782 blocks
constexpr int CHUNKS = 128;                      // mean segment split

typedef __attribute__((ext_vector_type(8))) short short8;   // bf16x8 MFMA A/B frag
typedef __attribute__((ext_vector_type(4))) float float4v;  // fp32x4 MFMA C/D frag

__device__ __forceinline__ short f2bf(float f) {
    union { float f; unsigned u; } v; v.f = f;
    unsigned r = v.u + 0x7fffu + ((v.u >> 16) & 1u);  // RNE
    return (short)(r >> 16);
}
__device__ __forceinline__ float bf2f(unsigned short s) {
    union { unsigned u; float f; } v; v.u = ((unsigned)s) << 16;
    return v.f;
}

// ---------------- consolidated init ----------------
__global__ __launch_bounds__(256) void init_kernel(
    const int* __restrict__ batch, const float* __restrict__ W1,
    const float* __restrict__ W2,
    int* __restrict__ cursor, float* __restrict__ rootlin,
    int* __restrict__ startv, int* __restrict__ cntg,
    short* __restrict__ Bt1, short* __restrict__ Bt2)
{
    __shared__ int s_start[N_GRAPHS + 1];
    const int t = threadIdx.x;
    const int gid = blockIdx.x * 256 + t;

    if (gid < N_NODES) cursor[gid] = 0;
    if (gid < N_GRAPHS * OUT_F) rootlin[gid] = 0.f;
    if (gid < 128 * IN_F) { // Bt1[n*256+k] = bf16(W1[k*128+n])
        int n = gid >> 8, k = gid & 255;
        Bt1[(size_t)n * IN_F + k] = f2bf(W1[(size_t)k * 128 + n]);
    } else if (gid < 128 * IN_F + 128 * HID_F) {
        int tw = gid - 128 * IN_F;
        int n = tw >> 7, k = tw & 127;
        Bt2[(size_t)n * HID_F + k] = f2bf(W2[(size_t)k * 128 + n]);
    }
    if (blockIdx.x == 0) {
        if (t <= N_GRAPHS) { // lower_bound(batch, g); g==128 -> N_NODES
            int g = t, lo = 0, hi = N_NODES;
            while (lo < hi) {
                int mid = (lo + hi) >> 1;
                if (batch[mid] < g) lo = mid + 1; else hi = mid;
            }
            s_start[t] = lo;
        }
        __syncthreads();
        if (t < N_GRAPHS) {
            startv[t] = s_start[t];
            cntg[t] = s_start[t + 1] - s_start[t];
        }
    }
}

__global__ void edge_prep_kernel(const int* __restrict__ dst, int* __restrict__ cntin, int E) {
    int e = blockIdx.x * blockDim.x + threadIdx.x;
    if (e < E) atomicAdd(&cntin[dst[e]], 1);
}

__global__ __launch_bounds__(1024) void scan_reduce_kernel(const int* __restrict__ cnt,
                                                           int* __restrict__ partial, int n) {
    __shared__ int sm[1024];
    int t = threadIdx.x;
    int i = blockIdx.x * 1024 + t;
    sm[t] = (i < n) ? cnt[i] : 0;
    __syncthreads();
    for (int ofs = 512; ofs > 0; ofs >>= 1) {
        if (t < ofs) sm[t] += sm[t + ofs];
        __syncthreads();
    }
    if (t == 0) partial[blockIdx.x] = sm[0];
}

// r7: scan_base folded in — each block computes its own base from the 196
// partials in LDS (uniform add loop, broadcast reads). Saves one launch.
// cnt aliases cur: each thread reads cnt[i] before writing cur[i] (same index).
__global__ __launch_bounds__(1024) void scan_final_kernel(const int* __restrict__ cnt,
                                                          const int* __restrict__ partial,
                                                          int* __restrict__ rp,
                                                          int* __restrict__ cur,
                                                          float* __restrict__ dinv, int n) {
    __shared__ int sm[1024];
    __shared__ int pb[SCAN_NB];
    int t = threadIdx.x;
    int i = blockIdx.x * 1024 + t;
    if (t < SCAN_NB) pb[t] = partial[t];
    int v = (i < n) ? cnt[i] : 0;
    sm[t] = v;
    __syncthreads();
    for (int ofs = 1; ofs < 1024; ofs <<= 1) {
        int u = (t >= ofs) ? sm[t - ofs] : 0;
        __syncthreads();
        sm[t] += u;
        __syncthreads();
    }
    int base = 0;
    for (int j = 0; j < blockIdx.x; ++j) base += pb[j];
    if (i < n) {
        int ex = base + sm[t] - v; // exclusive
        rp[i] = ex;
        cur[i] = ex;
        dinv[i] = rsqrtf(1.0f + (float)v);
        if (i == n - 1) rp[n] = ex + v;
    }
}

// Fused bucket + rootlin: blocks [0,782) bucket edges; blocks [782,1038)
// compute rootlin partial sums (64-k slices) via atomicAdd into zeroed rootlin.
__global__ __launch_bounds__(256) void bucket_rootlin_kernel(
    const int* __restrict__ src, const int* __restrict__ dst,
    int* __restrict__ cur, int* __restrict__ adj,
    const float* __restrict__ x, const int* __restrict__ root_index,
    const float* __restrict__ W2, float* __restrict__ rootlin)
{
    int b = blockIdx.x;
    int t = threadIdx.x;
    if (b < EDGE_NB) {
        int e = b * 256 + t;
        if (e < N_EDGES) {
            int pos = atomicAdd(&cur[dst[e]], 1);
            adj[pos] = src[e];
        }
    } else {
        int rb = b - EDGE_NB;          // 0..255
        int g = rb >> 1;
        int f = t & 127;
        int k0 = (rb & 1) * 128 + (t >> 7) * 64;
        int r = root_index[g];
        const float* xr = x + (size_t)r * IN_F;
        float acc = 0.f;
        for (int k = k0; k < k0 + 64; ++k)
            acc += fmaxf(xr[k], 0.f) * W2[(size_t)(HID_F + k) * OUT_F + f];
        atomicAdd(&rootlin[(size_t)g * OUT_F + f], acc);
    }
}

// ---------------- conv1: bf16 MFMA GEMM (A direct-from-global, B in LDS) ----------------
// hs1[M,128] = bf16( dinv .* (x[M,256] @ W1) )
__global__ __launch_bounds__(256, 4) void conv1_kernel(
    const float* __restrict__ Ap, const short* __restrict__ Bt,
    unsigned short* __restrict__ outp, const float* __restrict__ dinv)
{
    // stride 136 shorts = 272B: bank stride 68 == 4 mod 32 -> 2-way conflicts only (free, m136)
    __shared__ __align__(16) short Bs[128][136];

    const int tid = threadIdx.x;
    const int wave = tid >> 6;
    const int lane = tid & 63;
    const int quad = lane >> 4;
    const int l16  = lane & 15;
    const int row0 = blockIdx.x * 64;
    const int arow = row0 + wave * 16 + l16;  // this lane's A row (m89 layout)

    float4v acc[8];
    #pragma unroll
    for (int c = 0; c < 8; ++c) acc[c] = (float4v){0.f, 0.f, 0.f, 0.f};

    const int bn = tid >> 1;
    const int bk = (tid & 1) * 64;
    constexpr int KTOT = IN_F;

    for (int kb = 0; kb < 2; ++kb) {
        {
            const short* bp = Bt + (size_t)bn * KTOT + kb * 128 + bk;
            #pragma unroll
            for (int j = 0; j < 8; ++j)
                *(short8*)&Bs[bn][bk + 8 * j] = *(const short8*)(bp + 8 * j);
        }
        __syncthreads();
        #pragma unroll
        for (int ks = 0; ks < 4; ++ks) {
            // A frag direct from global: A[arow][kb*128 + ks*32 + quad*8 + j]
            const float* ap = Ap + (size_t)arow * KTOT + kb * 128 + ks * 32 + quad * 8;
            float4 f0 = *(const float4*)ap;
            float4 f1 = *(const float4*)(ap + 4);
            short8 af;
            af[0] = f2bf(f0.x); af[1] = f2bf(f0.y); af[2] = f2bf(f0.z); af[3] = f2bf(f0.w);
            af[4] = f2bf(f1.x); af[5] = f2bf(f1.y); af[6] = f2bf(f1.z); af[7] = f2bf(f1.w);
            #pragma unroll
            for (int c = 0; c < 8; ++c) {
                short8 bf = *(const short8*)&Bs[c * 16 + l16][ks * 32 + quad * 8];
                acc[c] = __builtin_amdgcn_mfma_f32_16x16x32_bf16(af, bf, acc[c], 0, 0, 0);
            }
        }
        if (kb == 0) __syncthreads(); // protect Bs rewrite
    }

    #pragma unroll
    for (int r = 0; r < 4; ++r) {
        int row = row0 + wave * 16 + quad * 4 + r;
        float di = dinv[row];
        #pragma unroll
        for (int c = 0; c < 8; ++c)
            outp[(size_t)row * 128 + c * 16 + l16] = (unsigned short)f2bf(acc[c][r] * di);
    }
}

// ---------------- conv2: fused per-lane gather + bf16 MFMA GEMM (r7) ----------------
// hs2[d] = bf16( dinv[d] .* ( relu(dinv[d]*(hs1[d]+sum_in hs1[adj])+b1) @ W2[0:128]
//                             + rootlin[batch[d]] ) )
// A-frags are LANE-PRIVATE (m89 layout: row=wave*16+l16, cols quad*8+ks*32), so the
// CSR gather runs per-lane with ZERO added barriers. B in LDS (r6-proven).
// Deletes hsag (-102 MB traffic, -1 launch); gather hits L3-resident hs1.
__global__ __launch_bounds__(256, 4) void conv2_fused_kernel(
    const unsigned short* __restrict__ hs1, const short* __restrict__ Bt,
    unsigned short* __restrict__ hs2,
    const float* __restrict__ dinv, const float* __restrict__ b1v,
    const float* __restrict__ rootlin, const int* __restrict__ batch,
    const int* __restrict__ rp, const int* __restrict__ adj)
{
    __shared__ __align__(16) short Bs[128][136];

    const int tid = threadIdx.x;
    const int wave = tid >> 6;
    const int lane = tid & 63;
    const int quad = lane >> 4;
    const int l16  = lane & 15;
    const int row0 = blockIdx.x * 64;
    const int arow = row0 + wave * 16 + l16;

    // stage B (KTOT=128) — loads issue before the gather, overlap under it
    {
        const int bn = tid >> 1;
        const int bk = (tid & 1) * 64;
        const short* bp = Bt + (size_t)bn * HID_F + bk;
        #pragma unroll
        for (int j = 0; j < 8; ++j)
            *(short8*)&Bs[bn][bk + 8 * j] = *(const short8*)(bp + 8 * j);
    }

    // per-lane gather: this lane's A cols are {quad*8 + ks*32 .. +7}, ks=0..3
    float sum[4][8];
    {
        const unsigned short* hp = hs1 + (size_t)arow * 128 + quad * 8;
        #pragma unroll
        for (int ks = 0; ks < 4; ++ks) {
            short8 h = *(const short8*)(hp + ks * 32);
            #pragma unroll
            for (int q = 0; q < 8; ++q) sum[ks][q] = bf2f((unsigned short)h[q]);
        }
        int e0 = rp[arow], e1 = rp[arow + 1];
        for (int e = e0; e < e1; ++e) {
            const unsigned short* qp = hs1 + (size_t)adj[e] * 128 + quad * 8;
            #pragma unroll
            for (int ks = 0; ks < 4; ++ks) {
                short8 h = *(const short8*)(qp + ks * 32);
                #pragma unroll
                for (int q = 0; q < 8; ++q) sum[ks][q] += bf2f((unsigned short)h[q]);
            }
        }
    }
    float di_a = dinv[arow];
    short8 af[4];
    #pragma unroll
    for (int ks = 0; ks < 4; ++ks) {
        const float* bv = b1v + quad * 8 + ks * 32;
        #pragma unroll
        for (int q = 0; q < 8; ++q)
            af[ks][q] = f2bf(fmaxf(di_a * sum[ks][q] + bv[q], 0.f));
    }

    __syncthreads(); // B staged; A-frags are lane-private, nothing else to wait on

    float4v acc[8];
    #pragma unroll
    for (int c = 0; c < 8; ++c) acc[c] = (float4v){0.f, 0.f, 0.f, 0.f};
    #pragma unroll
    for (int ks = 0; ks < 4; ++ks) {
        #pragma unroll
        for (int c = 0; c < 8; ++c) {
            short8 bf = *(const short8*)&Bs[c * 16 + l16][ks * 32 + quad * 8];
            acc[c] = __builtin_amdgcn_mfma_f32_16x16x32_bf16(af[ks], bf, acc[c], 0, 0, 0);
        }
    }

    // epilogue: D[row=quad*4+r][col=c*16+l16] (m89-verified C/D layout); bf16 store
    #pragma unroll
    for (int r = 0; r < 4; ++r) {
        int row = row0 + wave * 16 + quad * 4 + r;
        float di = dinv[row];
        const float* rl = rootlin + (size_t)batch[row] * 128;
        #pragma unroll
        for (int c = 0; c < 8; ++c) {
            int col = c * 16 + l16;
            hs2[(size_t)row * 128 + col] = (unsigned short)f2bf((acc[c][r] + rl[col]) * di);
        }
    }
}

// ---------------- mean (r7: vectorized 16B/lane) ----------------
// pmean[c][g][f] = chunk-sum over nodes of relu(dinv[i]*(hs2[i]+sum_in hs2[adj]) + b2)
// 128 thr = 2 waves; per wave 4 row-slots x 16 lanes x 8 cols (ushort8, 16B/lane);
// 8 rows in flight; LDS column-reduction -> pmean (plain stores).
// out[g,128:256] = n>0 ? dinv[r]*(hs1[r]+sum_in hs1[adj]) + b1 : 0   (c==0 blocks)
__global__ __launch_bounds__(128) void mean_kernel(
    const unsigned short* __restrict__ hs2, const unsigned short* __restrict__ hs1,
    const float* __restrict__ dinv, const float* __restrict__ b1v,
    const float* __restrict__ b2v, const int* __restrict__ root_index,
    const int* __restrict__ cnt, const int* __restrict__ start,
    const int* __restrict__ rp, const int* __restrict__ adj,
    float* __restrict__ pmean, float* __restrict__ out)
{
    __shared__ float sm[8][128];
    int g = blockIdx.x;
    int c = blockIdx.y;
    int t = threadIdx.x;       // 0..127
    int wv = t >> 6;           // wave 0/1
    int lane = t & 63;
    int sub = lane >> 4;       // row slot 0..3
    int l16 = lane & 15;
    int c0 = l16 * 8;          // col base, 8 cols per lane

    int s = start[g], n = cnt[g];
    int per = (n + CHUNKS - 1) / CHUNKS;
    int lo = s + c * per;
    int hi = min(s + n, lo + per);

    float bb[8];
    #pragma unroll
    for (int q = 0; q < 8; ++q) bb[q] = b2v[c0 + q];

    float accv[8];
    #pragma unroll
    for (int q = 0; q < 8; ++q) accv[q] = 0.f;

    for (int i = lo + wv * 4 + sub; i < hi; i += 8) {
        float v[8];
        short8 h = *(const short8*)(hs2 + (size_t)i * 128 + c0);
        #pragma unroll
        for (int q = 0; q < 8; ++q) v[q] = bf2f((unsigned short)h[q]);
        int e0 = rp[i], e1 = rp[i + 1];
        for (int e = e0; e < e1; ++e) {
            short8 ha = *(const short8*)(hs2 + (size_t)adj[e] * 128 + c0);
            #pragma unroll
            for (int q = 0; q < 8; ++q) v[q] += bf2f((unsigned short)ha[q]);
        }
        float di = dinv[i];
        #pragma unroll
        for (int q = 0; q < 8; ++q) accv[q] += fmaxf(di * v[q] + bb[q], 0.f);
    }

    // column-reduce the 8 row-slots
    #pragma unroll
    for (int q = 0; q < 8; ++q) sm[wv * 4 + sub][c0 + q] = accv[q];
    __syncthreads();
    {
        float s2 = 0.f;
        #pragma unroll
        for (int r = 0; r < 8; ++r) s2 += sm[r][t];
        pmean[(size_t)c * (N_GRAPHS * 128) + g * 128 + t] = s2;
    }

    if (c == 0) { // root gather for out[g,128:256] (tiny: 128 graphs)
        int r = root_index[g];
        float v = 0.f;
        if (n > 0) {
            v = bf2f(hs1[(size_t)r * 128 + t]);
            int e0 = rp[r], e1 = rp[r + 1];
            for (int e = e0; e < e1; ++e)
                v += bf2f(hs1[(size_t)adj[e] * 128 + t]);
            v = dinv[r] * v + b1v[t];
        }
        out[(size_t)g * OUT_W + HID_F + t] = v;
    }
}

// out[g,0:128] = (1/n) * sum_c pmean[c][g][f]
__global__ void meanreduce_kernel(const float* __restrict__ pmean,
                                  const int* __restrict__ cnt,
                                  float* __restrict__ out)
{
    int g = blockIdx.x;
    int f = threadIdx.x;
    float s = 0.f;
    for (int c = 0; c < CHUNKS; ++c)
        s += pmean[(size_t)c * (N_GRAPHS * 128) + g * 128 + f];
    out[(size_t)g * OUT_W + f] = s / (float)max(cnt[g], 1);
}

// ---------------- launch ----------------

static inline size_t align_up(size_t x, size_t a) { return (x + a - 1) / a * a; }

extern "C" void kernel_launch(void* const* d_in, const int* in_sizes, int n_in,
                              void* d_out, int out_size, void* d_ws, size_t ws_size,
                              hipStream_t stream) {
    const float* x = (const float*)d_in[0];
    const int* ei = (const int*)d_in[1];
    const int* batch = (const int*)d_in[2];
    const int* root = (const int*)d_in[3];
    const float* W1 = (const float*)d_in[4];
    const float* b1 = (const float*)d_in[5];
    const float* W2 = (const float*)d_in[6];
    const float* b2 = (const float*)d_in[7];
    float* out = (float*)d_out;

    const int* src = ei;
    const int* dst = ei + N_EDGES;

    // workspace carve-up
    char* ws = (char*)d_ws;
    size_t off = 0;
    const size_t NB16 = (size_t)N_NODES * 128 * sizeof(unsigned short); // 51.2 MB

    float* dinv = (float*)(ws + off);    off = align_up(off + (size_t)N_NODES * sizeof(float), 256);
    int* cntg = (int*)(ws + off);        off = align_up(off + N_GRAPHS * sizeof(int), 256);
    int* startv = (int*)(ws + off);      off = align_up(off + N_GRAPHS * sizeof(int), 256);
    float* rootlin = (float*)(ws + off); off = align_up(off + (size_t)N_GRAPHS * OUT_F * sizeof(float), 256);
    short* Bt1 = (short*)(ws + off);     off = align_up(off + (size_t)128 * IN_F * sizeof(short), 256);
    short* Bt2 = (short*)(ws + off);     off = align_up(off + (size_t)128 * HID_F * sizeof(short), 256);
    int* rowptr = (int*)(ws + off);      off = align_up(off + (size_t)(N_NODES + 1) * sizeof(int), 256);
    int* cursor = (int*)(ws + off);      off = align_up(off + (size_t)N_NODES * sizeof(int), 256);
    int* partial = (int*)(ws + off);     off = align_up(off + (size_t)SCAN_NB * sizeof(int), 256);
    int* adj = (int*)(ws + off);         off = align_up(off + (size_t)N_EDGES * sizeof(int), 256);
    float* pmean = (float*)(ws + off);   off = align_up(off + (size_t)CHUNKS * N_GRAPHS * 128 * sizeof(float), 256);
    unsigned short* hs1 = (unsigned short*)(ws + off);  off = align_up(off + NB16, 256);
    unsigned short* hs2 = (unsigned short*)(ws + off);  off = align_up(off + NB16, 256);
    (void)ws_size; (void)n_in; (void)in_sizes; (void)out_size;

    // consolidated init: cursor-zero, rootlin-zero, bounds, weight transposes
    init_kernel<<<EDGE_NB, 256, 0, stream>>>(batch, W1, W2, cursor, rootlin,
                                             startv, cntg, Bt1, Bt2);
    // in-degree -> CSR-by-dst (scan_base folded into scan_final)
    edge_prep_kernel<<<EDGE_NB, 256, 0, stream>>>(dst, cursor, N_EDGES);
    scan_reduce_kernel<<<SCAN_NB, 1024, 0, stream>>>(cursor, partial, N_NODES);
    scan_final_kernel<<<SCAN_NB, 1024, 0, stream>>>(cursor, partial, rowptr, cursor, dinv, N_NODES);
    // bucket edges + rootlin in one launch
    bucket_rootlin_kernel<<<EDGE_NB + 2 * N_GRAPHS, 256, 0, stream>>>(
        src, dst, cursor, adj, x, root, W2, rootlin);

    // conv1 linear: hs1 = bf16( dinv .* (x @ W1) )
    conv1_kernel<<<N_NODES / 64, 256, 0, stream>>>(x, Bt1, hs1, dinv);

    // conv2: per-lane CSR gather fused into A-frag load + streaming MFMA GEMM
    conv2_fused_kernel<<<N_NODES / 64, 256, 0, stream>>>(
        hs1, Bt2, hs2, dinv, b1, rootlin, batch, rowptr, adj);

    // conv2-aggregation + relu + graph mean partials + root gather (vectorized)
    dim3 mg(N_GRAPHS, CHUNKS);
    mean_kernel<<<mg, 128, 0, stream>>>(hs2, hs1, dinv, b1, b2, root, cntg, startv,
                                        rowptr, adj, pmean, out);
    meanreduce_kernel<<<N_GRAPHS, 128, 0, stream>>>(pmean, cntg, out);
}